// Round 10
// baseline (485.760 us; speedup 1.0000x reference)
//
#include <hip/hip_runtime.h>
#include <hip/hip_bf16.h>

#define B_   16
#define CIN  256
#define COUT 256
#define HH   64
#define WW   64
#define WDIM 512
#define OH   128
#define OW   128

#define REPC 8    // conv diagnostic repeat
#define REPU 16   // upsample diagnostic repeat

typedef __attribute__((ext_vector_type(8))) short short8;
typedef __attribute__((ext_vector_type(4))) float f32x4;

__device__ __forceinline__ unsigned short f2bf(float f) {
    __hip_bfloat16 h = __float2bfloat16(f);
    return *reinterpret_cast<unsigned short*>(&h);
}
__device__ __forceinline__ float bf2f(unsigned short u) {
    unsigned int t = ((unsigned int)u) << 16;
    return *reinterpret_cast<float*>(&t);
}

// ws layout: bytes [0..16640) float scratch (sumsq partials + styles)
//            byte 32768:  wb bf16 [16][256 o][256 i]        (2 MB)
//            byte 4 MiB:  y  bf16 [16][256 o][64][64]       (33.5 MB)

__global__ __launch_bounds__(256) void k_styles(const float* __restrict__ w,
                                                const float* __restrict__ aw,
                                                const float* __restrict__ ab,
                                                float* __restrict__ ws) {
    int b = blockIdx.x, i = threadIdx.x;
    const float4* wr = (const float4*)(w + b * WDIM);
    const float4* ar = (const float4*)(aw + (size_t)i * WDIM);
    float acc = 0.f;
    #pragma unroll 4
    for (int k = 0; k < WDIM / 4; ++k) {
        float4 wv = wr[k], av = ar[k];
        acc += wv.x * av.x + wv.y * av.y + wv.z * av.z + wv.w * av.w;
    }
    const float wg = 0.04419417382415922f; // 1/sqrt(512)
    float st = acc * wg + ab[i];
    ws[64 + b * CIN + i] = st;
    __shared__ float sred[256];
    sred[i] = st * st;
    __syncthreads();
    for (int s = 128; s > 0; s >>= 1) {
        if (i < s) sred[i] += sred[i + s];
        __syncthreads();
    }
    if (i == 0) ws[b] = sred[0];
}

__global__ __launch_bounds__(64) void k_wb(const float* __restrict__ weight,
                                           const float* __restrict__ ws,
                                           unsigned short* __restrict__ wb) {
    int o = blockIdx.x, b = blockIdx.y, l = threadIdx.x;
    float tot = 0.f;
    #pragma unroll
    for (int j = 0; j < B_; ++j) tot += ws[j];
    float srs = rsqrtf(tot / (float)(B_ * CIN));
    float4 wk = *(const float4*)(weight + (size_t)o * CIN + l * 4);
    float ss = wk.x * wk.x + wk.y * wk.y + wk.z * wk.z + wk.w * wk.w;
    #pragma unroll
    for (int off = 32; off; off >>= 1) ss += __shfl_xor(ss, off);
    float wkn = rsqrtf(ss / (float)CIN);
    float4 st = *(const float4*)(ws + 64 + b * CIN + l * 4);
    float4 t;
    t.x = wk.x * wkn * st.x * srs;
    t.y = wk.y * wkn * st.y * srs;
    t.z = wk.z * wkn * st.z * srs;
    t.w = wk.w * wkn * st.w * srs;
    float s2 = t.x * t.x + t.y * t.y + t.z * t.z + t.w * t.w;
    #pragma unroll
    for (int off = 32; off; off >>= 1) s2 += __shfl_xor(s2, off);
    float dcoef = rsqrtf(s2 + 1e-8f);
    ushort4 pk;
    pk.x = f2bf(t.x * dcoef);
    pk.y = f2bf(t.y * dcoef);
    pk.z = f2bf(t.z * dcoef);
    pk.w = f2bf(t.w * dcoef);
    *(ushort4*)(wb + ((size_t)b * COUT + o) * CIN + l * 4) = pk;
}

// Conv5 (R8 structure) x REPC diagnostic repeat.
__global__ __launch_bounds__(512, 4) void k_conv5(const float* __restrict__ x,
                                                  const float* __restrict__ bias,
                                                  const unsigned short* __restrict__ wb,
                                                  unsigned short* __restrict__ y,
                                                  int rep) {
    __shared__ __align__(16) unsigned short xt[128 * CIN]; // 65536 B
    const int r2 = blockIdx.x * 2;
    const int b = blockIdx.y;
    const int tid = threadIdx.x;
    const int lane = tid & 63;
    const int wv = tid >> 6;
    const int lo = lane & 15, hi = lane >> 4;

    #pragma unroll 1
    for (int rp = 0; rp < rep; ++rp) {
        const unsigned short* wbb = wb + (size_t)b * COUT * CIN;
        short8 breg[2][8];
        #pragma unroll
        for (int c = 0; c < 2; ++c) {
            const int m0 = (wv * 2 + c) * 16;
            const unsigned short* wrow = wbb + (size_t)(m0 + lo) * CIN + hi * 8;
            #pragma unroll
            for (int ks = 0; ks < 8; ++ks)
                breg[c][ks] = *(const short8*)(wrow + ks * 32);
        }

        {
            const int c4 = tid & 15;
            const int rowsel = (tid >> 4) & 1;
            const int ig = tid >> 5;
            const float* xp = x + (size_t)b * CIN * (HH * WW) + (size_t)(r2 + rowsel) * WW + c4 * 4;
            const int pxbase = rowsel * 64 + c4 * 4;
            #pragma unroll
            for (int p = 0; p < 8; ++p) {
                const int i0 = ig * 16 + p * 2;
                float4 v0 = *(const float4*)(xp + (size_t)i0 * (HH * WW));
                float4 v1 = *(const float4*)(xp + (size_t)(i0 + 1) * (HH * WW));
                const int ib = i0 >> 3, e = i0 & 7;
                #pragma unroll
                for (int j = 0; j < 4; ++j) {
                    const int px = pxbase + j;
                    float f0 = (j == 0) ? v0.x : (j == 1) ? v0.y : (j == 2) ? v0.z : v0.w;
                    float f1 = (j == 0) ? v1.x : (j == 1) ? v1.y : (j == 2) ? v1.z : v1.w;
                    unsigned int pk = (unsigned int)f2bf(f0) | ((unsigned int)f2bf(f1) << 16);
                    const int swz = ib ^ (px & 31) ^ ((px >> 2) & 7);
                    *(unsigned int*)&xt[px * 256 + (swz << 3) + e] = pk;
                }
            }
        }
        __syncthreads();

        unsigned short* yb = y + (size_t)b * COUT * (HH * WW);

        #pragma unroll
        for (int c = 0; c < 2; ++c) {
            const int m0 = (wv * 2 + c) * 16;
            const float bs = bias[m0 + lo];
            unsigned short* yrow = yb + (size_t)(m0 + lo) * (HH * WW);
            #pragma unroll
            for (int g = 0; g < 8; ++g) {
                f32x4 acc = {0.f, 0.f, 0.f, 0.f};
                #pragma unroll
                for (int ks = 0; ks < 8; ++ks) {
                    const int px = g * 16 + lo;
                    const int ib = ks * 4 + hi;
                    const int swz = ib ^ (px & 31) ^ ((px >> 2) & 7);
                    short8 a = *(const short8*)&xt[px * 256 + (swz << 3)];
                    acc = __builtin_amdgcn_mfma_f32_16x16x32_bf16(a, breg[c][ks], acc, 0, 0, 0);
                }
                ushort4 pk;
                pk.x = f2bf(acc[0] + bs);
                pk.y = f2bf(acc[1] + bs);
                pk.z = f2bf(acc[2] + bs);
                pk.w = f2bf(acc[3] + bs);
                const int prow = g >> 2;
                const int pcol = (g & 3) * 16 + hi * 4;
                *(ushort4*)(yrow + (size_t)(r2 + prow) * WW + pcol) = pk;
            }
        }
        __syncthreads();   // protect xt from next-iter staging WAR
        asm volatile("" ::: "memory");
    }
}

// Upsample (R8 structure) x REPU diagnostic repeat.
__global__ __launch_bounds__(256, 8) void k_up(const unsigned short* __restrict__ y,
                                               float* __restrict__ out,
                                               int rep) {
    const int tid = threadIdx.x;
    const int t = tid & 31;
    const int s = tid >> 5;
    const int idx = blockIdx.x * 8 + s;
    const int p = idx & 63;
    const int ch = (idx >> 6) & 255;
    const int b = idx >> 14;

    #pragma unroll 1
    for (int rp = 0; rp < rep; ++rp) {
        const unsigned short* yb = y + (size_t)(b * COUT + ch) * (HH * WW);
        const int pm1 = max(p - 1, 0), pp1 = min(p + 1, HH - 1);
        unsigned int T  = *(const unsigned int*)(yb + pm1 * WW + 2 * t);
        unsigned int M  = *(const unsigned int*)(yb + p   * WW + 2 * t);
        unsigned int Bt = *(const unsigned int*)(yb + pp1 * WW + 2 * t);

        float tB = bf2f((unsigned short)(T & 0xffff)),  tC = bf2f((unsigned short)(T >> 16));
        float mB = bf2f((unsigned short)(M & 0xffff)),  mC = bf2f((unsigned short)(M >> 16));
        float bB = bf2f((unsigned short)(Bt & 0xffff)), bC = bf2f((unsigned short)(Bt >> 16));

        float aB = 0.25f * tB + 0.75f * mB, aC = 0.25f * tC + 0.75f * mC;
        float eB = 0.75f * mB + 0.25f * bB, eC = 0.75f * mC + 0.25f * bC;

        float aA = __shfl_up(aC, 1, 32);   if (t == 0)  aA = aB;
        float aD = __shfl_down(aB, 1, 32); if (t == 31) aD = aC;
        float eA = __shfl_up(eC, 1, 32);   if (t == 0)  eA = eB;
        float eD = __shfl_down(eB, 1, 32); if (t == 31) eD = eC;

        float4 o0, o1;
        o0.x = 0.25f * aA + 0.75f * aB;
        o0.y = 0.75f * aB + 0.25f * aC;
        o0.z = 0.25f * aB + 0.75f * aC;
        o0.w = 0.75f * aC + 0.25f * aD;
        o1.x = 0.25f * eA + 0.75f * eB;
        o1.y = 0.75f * eB + 0.25f * eC;
        o1.z = 0.25f * eB + 0.75f * eC;
        o1.w = 0.75f * eC + 0.25f * eD;

        float* op = out + (size_t)(b * COUT + ch) * (OH * OW) + (2 * p) * OW + 4 * t;
        *(float4*)op = o0;
        *(float4*)(op + OW) = o1;
        asm volatile("" ::: "memory");
    }
}

extern "C" void kernel_launch(void* const* d_in, const int* in_sizes, int n_in,
                              void* d_out, int out_size, void* d_ws, size_t ws_size,
                              hipStream_t stream) {
    (void)in_sizes; (void)n_in; (void)out_size; (void)ws_size;
    const float* x      = (const float*)d_in[0];
    const float* w      = (const float*)d_in[1];
    const float* aw     = (const float*)d_in[2];
    const float* ab     = (const float*)d_in[3];
    const float* weight = (const float*)d_in[4];
    const float* bias   = (const float*)d_in[5];
    float* out = (float*)d_out;
    float* wsf = (float*)d_ws;
    unsigned short* wb = (unsigned short*)((char*)d_ws + 32768);
    unsigned short* y  = (unsigned short*)((char*)d_ws + (4u << 20));

    hipLaunchKernelGGL(k_styles, dim3(16), dim3(256), 0, stream, w, aw, ab, wsf);
    hipLaunchKernelGGL(k_wb, dim3(COUT, B_), dim3(64), 0, stream, weight, wsf, wb);
    hipLaunchKernelGGL(k_conv5, dim3(HH / 2, B_), dim3(512), 0, stream, x, bias, wb, y, REPC);
    hipLaunchKernelGGL(k_up, dim3(B_ * COUT * HH / 8), dim3(256), 0, stream, y, out, REPU);
}

// Round 11
// 120.356 us; speedup vs baseline: 4.0360x; 4.0360x over previous
//
#include <hip/hip_runtime.h>
#include <hip/hip_bf16.h>

#define B_   16
#define CIN  256
#define COUT 256
#define HH   64
#define WW   64
#define WDIM 512
#define OH   128
#define OW   128

typedef __attribute__((ext_vector_type(8))) short short8;
typedef __attribute__((ext_vector_type(4))) float f32x4;

__device__ __forceinline__ unsigned short f2bf(float f) {
    __hip_bfloat16 h = __float2bfloat16(f);
    return *reinterpret_cast<unsigned short*>(&h);
}
__device__ __forceinline__ float bf2f(unsigned short u) {
    unsigned int t = ((unsigned int)u) << 16;
    return *reinterpret_cast<float*>(&t);
}

// ws layout: bytes [0..16640) float scratch (sumsq partials + styles)
//            byte 32768: wb bf16 [16][256 o][256 i]  (2 MB)

__global__ __launch_bounds__(256) void k_styles(const float* __restrict__ w,
                                                const float* __restrict__ aw,
                                                const float* __restrict__ ab,
                                                float* __restrict__ ws) {
    int b = blockIdx.x, i = threadIdx.x;
    const float4* wr = (const float4*)(w + b * WDIM);
    const float4* ar = (const float4*)(aw + (size_t)i * WDIM);
    float acc = 0.f;
    #pragma unroll 4
    for (int k = 0; k < WDIM / 4; ++k) {
        float4 wv = wr[k], av = ar[k];
        acc += wv.x * av.x + wv.y * av.y + wv.z * av.z + wv.w * av.w;
    }
    const float wg = 0.04419417382415922f; // 1/sqrt(512)
    float st = acc * wg + ab[i];
    ws[64 + b * CIN + i] = st;
    __shared__ float sred[256];
    sred[i] = st * st;
    __syncthreads();
    for (int s = 128; s > 0; s >>= 1) {
        if (i < s) sred[i] += sred[i + s];
        __syncthreads();
    }
    if (i == 0) ws[b] = sred[0];
}

__global__ __launch_bounds__(64) void k_wb(const float* __restrict__ weight,
                                           const float* __restrict__ ws,
                                           unsigned short* __restrict__ wb) {
    int o = blockIdx.x, b = blockIdx.y, l = threadIdx.x;
    float tot = 0.f;
    #pragma unroll
    for (int j = 0; j < B_; ++j) tot += ws[j];
    float srs = rsqrtf(tot / (float)(B_ * CIN));
    float4 wk = *(const float4*)(weight + (size_t)o * CIN + l * 4);
    float ss = wk.x * wk.x + wk.y * wk.y + wk.z * wk.z + wk.w * wk.w;
    #pragma unroll
    for (int off = 32; off; off >>= 1) ss += __shfl_xor(ss, off);
    float wkn = rsqrtf(ss / (float)CIN);
    float4 st = *(const float4*)(ws + 64 + b * CIN + l * 4);
    float4 t;
    t.x = wk.x * wkn * st.x * srs;
    t.y = wk.y * wkn * st.y * srs;
    t.z = wk.z * wkn * st.z * srs;
    t.w = wk.w * wkn * st.w * srs;
    float s2 = t.x * t.x + t.y * t.y + t.z * t.z + t.w * t.w;
    #pragma unroll
    for (int off = 32; off; off >>= 1) s2 += __shfl_xor(s2, off);
    float dcoef = rsqrtf(s2 + 1e-8f);
    ushort4 pk;
    pk.x = f2bf(t.x * dcoef);
    pk.y = f2bf(t.y * dcoef);
    pk.z = f2bf(t.z * dcoef);
    pk.w = f2bf(t.w * dcoef);
    *(ushort4*)(wb + ((size_t)b * COUT + o) * CIN + l * 4) = pk;
}

// Fused conv + bilinear-2x upsample.
// Block (r,b): stage x rows {r, min(r+1,63)} (128 px x 256 ch) into swizzled
// xt; 8 waves split o (wave wv owns o-chunks {2wv, 2wv+1}, wb loaded once);
// y bf16 -> rotation-swizzled yl LDS; epilogue emits out rows {2r+1, 2r+2}
// (block 0 adds row 0, block 63 only row 127). y never touches HBM.
__global__ __launch_bounds__(512, 2) void k_fused(const float* __restrict__ x,
                                                  const float* __restrict__ bias,
                                                  const unsigned short* __restrict__ wb,
                                                  float* __restrict__ out) {
    __shared__ __align__(16) unsigned short xt[128 * CIN]; // 65536 B
    __shared__ __align__(16) unsigned int yl[COUT * 64];   // 65536 B
    const int r = blockIdx.x;
    const int b = blockIdx.y;
    const int tid = threadIdx.x;
    const int lane = tid & 63;
    const int wv = tid >> 6;
    const int lo = lane & 15, hi = lane >> 4;

    // ---- prefetch c=0 wb B-frags before staging (latency hidden) ----
    const unsigned short* wbb = wb + (size_t)b * COUT * CIN;
    const int m0_0 = (wv * 2 + 0) * 16;
    const int m0_1 = (wv * 2 + 1) * 16;
    short8 breg0[8], breg1[8];
    {
        const unsigned short* wrow = wbb + (size_t)(m0_0 + lo) * CIN + hi * 8;
        #pragma unroll
        for (int ks = 0; ks < 8; ++ks) breg0[ks] = *(const short8*)(wrow + ks * 32);
    }

    // ---- stage x rows {r, min(r+1,63)} -> swizzled bf16 [px][i] ----
    // xt u16 idx = px*256 + (swz<<3) + (i&7), ib=i>>3,
    // swz = ib ^ (px&31) ^ ((px>>2)&7)
    {
        const int c4 = tid & 15;
        const int rowsel = (tid >> 4) & 1;
        const int ig = tid >> 5;
        const int grow = min(r + rowsel, HH - 1);
        const float* xp = x + (size_t)b * CIN * (HH * WW) + (size_t)grow * WW + c4 * 4;
        const int pxbase = rowsel * 64 + c4 * 4;
        #pragma unroll
        for (int p = 0; p < 8; ++p) {
            const int i0 = ig * 16 + p * 2;
            float4 v0 = *(const float4*)(xp + (size_t)i0 * (HH * WW));
            float4 v1 = *(const float4*)(xp + (size_t)(i0 + 1) * (HH * WW));
            const int ib = i0 >> 3, e = i0 & 7;
            #pragma unroll
            for (int j = 0; j < 4; ++j) {
                const int px = pxbase + j;
                float f0 = (j == 0) ? v0.x : (j == 1) ? v0.y : (j == 2) ? v0.z : v0.w;
                float f1 = (j == 0) ? v1.x : (j == 1) ? v1.y : (j == 2) ? v1.z : v1.w;
                unsigned int pk = (unsigned int)f2bf(f0) | ((unsigned int)f2bf(f1) << 16);
                const int swz = ib ^ (px & 31) ^ ((px >> 2) & 7);
                *(unsigned int*)&xt[px * 256 + (swz << 3) + e] = pk;
            }
        }
    }
    __syncthreads();

    // issue c=1 wb loads now (overlap with c=0 MFMAs)
    {
        const unsigned short* wrow = wbb + (size_t)(m0_1 + lo) * CIN + hi * 8;
        #pragma unroll
        for (int ks = 0; ks < 8; ++ks) breg1[ks] = *(const short8*)(wrow + ks * 32);
    }

    // ---- MFMA + write y into rotation-swizzled yl ----
    // y u32 col for px-pair p2 of output row o: (p2 + 2*(o&15)) & 63
    #pragma unroll
    for (int c = 0; c < 2; ++c) {
        const int m0 = c ? m0_1 : m0_0;
        const int o = m0 + lo;
        const float bs = bias[o];
        const int rot = 2 * (o & 15);
        unsigned int* yrow = &yl[o * 64];
        #pragma unroll
        for (int g = 0; g < 8; ++g) {
            f32x4 acc = {0.f, 0.f, 0.f, 0.f};
            #pragma unroll
            for (int ks = 0; ks < 8; ++ks) {
                const int px = g * 16 + lo;
                const int ib = ks * 4 + hi;
                const int swz = ib ^ (px & 31) ^ ((px >> 2) & 7);
                short8 a = *(const short8*)&xt[px * 256 + (swz << 3)];
                acc = __builtin_amdgcn_mfma_f32_16x16x32_bf16(
                        a, c ? breg1[ks] : breg0[ks], acc, 0, 0, 0);
            }
            // D: col(o)=lo, row(px)=hi*4+j -> px pair p2 = g*8 + hi*2
            const int p2 = g * 8 + hi * 2;
            unsigned int u0 = (unsigned int)f2bf(acc[0] + bs) | ((unsigned int)f2bf(acc[1] + bs) << 16);
            unsigned int u1 = (unsigned int)f2bf(acc[2] + bs) | ((unsigned int)f2bf(acc[3] + bs) << 16);
            const int cc = (p2 + rot) & 63;
            yrow[cc] = u0;
            yrow[cc + 1] = u1;
        }
    }
    __syncthreads();

    // ---- epilogue: bilinear 2x upsample from yl, write out rows ----
    const int ostart = (r == 0) ? 0 : (2 * r + 1);
    const int nrows = (r == 0) ? 3 : ((r == HH - 1) ? 1 : 2);
    const int iters = nrows * 16;
    const int h = tid >> 5;    // half-wave 0..15
    const int t = tid & 31;    // col-pair lane

    for (int i = 0; i < iters; ++i) {
        const int task = i * 16 + h;
        const int o = task & 255;
        const int ori = task >> 8;
        const int orow = ostart + ori;
        const int yr0 = (orow - 1) >> 1;                 // arith shift: -1 for orow=0
        const int lr0 = min(max(yr0, 0), HH - 1) - r;    // 0 or 1
        const int lr1 = min(yr0 + 1, HH - 1) - r;        // 0 or 1
        const float wr0 = (orow & 1) ? 0.75f : 0.25f;
        const float wr1 = 1.f - wr0;
        const int rot = 2 * (o & 15);
        const unsigned int* yrow = &yl[o * 64];
        unsigned int M0 = yrow[(lr0 * 32 + t + rot) & 63];
        unsigned int M1 = yrow[(lr1 * 32 + t + rot) & 63];
        float mB = bf2f((unsigned short)(M0 & 0xffff)), mC = bf2f((unsigned short)(M0 >> 16));
        float nB = bf2f((unsigned short)(M1 & 0xffff)), nC = bf2f((unsigned short)(M1 >> 16));
        float vB = wr0 * mB + wr1 * nB;
        float vC = wr0 * mC + wr1 * nC;
        float vA = __shfl_up(vC, 1, 32);   if (t == 0)  vA = vB;
        float vD = __shfl_down(vB, 1, 32); if (t == 31) vD = vC;
        float4 ov;
        ov.x = 0.25f * vA + 0.75f * vB;
        ov.y = 0.75f * vB + 0.25f * vC;
        ov.z = 0.25f * vB + 0.75f * vC;
        ov.w = 0.75f * vC + 0.25f * vD;
        float* op = out + (((size_t)(b * COUT + o) * OH) + orow) * OW + 4 * t;
        *(float4*)op = ov;
    }
}

extern "C" void kernel_launch(void* const* d_in, const int* in_sizes, int n_in,
                              void* d_out, int out_size, void* d_ws, size_t ws_size,
                              hipStream_t stream) {
    (void)in_sizes; (void)n_in; (void)out_size; (void)ws_size;
    const float* x      = (const float*)d_in[0];
    const float* w      = (const float*)d_in[1];
    const float* aw     = (const float*)d_in[2];
    const float* ab     = (const float*)d_in[3];
    const float* weight = (const float*)d_in[4];
    const float* bias   = (const float*)d_in[5];
    float* out = (float*)d_out;
    float* wsf = (float*)d_ws;
    unsigned short* wb = (unsigned short*)((char*)d_ws + 32768);

    hipLaunchKernelGGL(k_styles, dim3(16), dim3(256), 0, stream, w, aw, ab, wsf);
    hipLaunchKernelGGL(k_wb, dim3(COUT, B_), dim3(64), 0, stream, weight, wsf, wb);
    hipLaunchKernelGGL(k_fused, dim3(HH, B_), dim3(512), 0, stream, x, bias, wb, out);
}